// Round 10
// baseline (1995.703 us; speedup 1.0000x reference)
//
#include <hip/hip_runtime.h>
#include <math.h>

// CausalVisionMamba — round 10: batched-token patch embed (register-cached
// weight rows, LDS im2col); everything else unchanged from round 9.

namespace {
constexpr int NB = 4;
constexpr int SL = 3136;
constexpr int DM = 384;
constexpr int DI = 768;
constexpr int DSN = 16;
constexpr int DR = 24;
constexpr int NLAYER = 4;
constexpr int NCLS = 1000;
constexpr int XPN = DR + 2 * DSN;  // 56
constexpr int NCHAIN = NB * DI;    // 3072
constexpr int PTOK = 32;           // tokens per patch-embed block
}

typedef float f32x4 __attribute__((ext_vector_type(4)));
typedef short short8 __attribute__((ext_vector_type(8)));
typedef short short4v __attribute__((ext_vector_type(4)));

__device__ __forceinline__ float siluf(float x) { return x / (1.f + expf(-x)); }
__device__ __forceinline__ float softplusf(float x) {
  return fmaxf(x, 0.f) + log1pf(expf(-fabsf(x)));
}
__device__ __forceinline__ unsigned short cvt_bf(float f) {
  unsigned int x = __float_as_uint(f);
  unsigned int r = (x + 0x7fffu + ((x >> 16) & 1u)) >> 16;  // RNE
  return (unsigned short)r;
}

// ---------------- patch embed: t[b][l][dm] fp32 + tb bf16 ----------------
// 32 tokens/block, 128 threads. LDS im2col; weight row cached in 12 float4.
__global__ __launch_bounds__(128) void k_patch(
    const float* __restrict__ x, const float* __restrict__ w,
    const float* __restrict__ bias, float* __restrict__ t,
    unsigned short* __restrict__ tb) {
  __shared__ float patch[PTOK][48];
  const int tid = threadIdx.x;
  const int m0 = blockIdx.x * PTOK;
  const int b = m0 / SL, lbase = m0 % SL;
  // im2col: 32 tokens x 12 float4 chunks = 384 chunks, 3 per thread
#pragma unroll
  for (int i = 0; i < 3; ++i) {
    const int c = tid + i * 128;
    const int tok = c / 12, r = c % 12;
    const int ch = r >> 2, kh = r & 3;
    const int l = lbase + tok;
    const int hh = l / 56, ww = l % 56;
    const float4 v =
        *(const float4*)&x[((size_t)(b * 3 + ch) * 224 + (hh * 4 + kh)) * 224 + ww * 4];
    *(float4*)&patch[tok][ch * 16 + kh * 4] = v;
  }
  __syncthreads();
#pragma unroll
  for (int i = 0; i < 3; ++i) {
    const int dm = tid + i * 128;
    float4 wr[12];
    const float4* w4 = (const float4*)(w + (size_t)dm * 48);
#pragma unroll
    for (int q = 0; q < 12; ++q) wr[q] = w4[q];
    const float bv = bias[dm];
#pragma unroll
    for (int tok = 0; tok < PTOK; ++tok) {
      float acc = bv;
      const float4* pr = (const float4*)&patch[tok][0];
#pragma unroll
      for (int q = 0; q < 12; ++q) {
        const float4 pv = pr[q];
        acc = fmaf(pv.x, wr[q].x, acc);
        acc = fmaf(pv.y, wr[q].y, acc);
        acc = fmaf(pv.z, wr[q].z, acc);
        acc = fmaf(pv.w, wr[q].w, acc);
      }
      const size_t o = ((size_t)(m0 + tok)) * DM + dm;
      t[o] = acc;
      tb[o] = cvt_bf(acc);
    }
  }
}

// ---------------- bf16 MFMA GEMM: D = A[M,K](bf16) * W[N,K]^T(fp32->bf16) -------
template <int BM, int BN, int MEPI, int NCAP, bool AT>
__global__ __launch_bounds__(256) void k_mgemm(
    const unsigned short* __restrict__ A, const float* __restrict__ Afp,
    const float* __restrict__ W, float* __restrict__ out,
    float* __restrict__ out2, unsigned short* __restrict__ outb, const int K) {
  constexpr int WM = BM / 2, WN = BN / 2, FM = WM / 16, FN = WN / 16;
  constexpr bool NMASK = (NCAP % BN) != 0;
  __shared__ unsigned short As[BM * 40];
  __shared__ unsigned short Bs[BN * 40];
  const int tid = threadIdx.x;
  const int lane = tid & 63, wave = tid >> 6;
  const int wm = wave >> 1, wn = wave & 1;
  const int m0 = blockIdx.x * BM, n0 = blockIdx.y * BN;
  const int r16 = lane & 15, kg = (lane >> 4) * 8;
  f32x4 acc[FM][FN] = {};
  const int nk = K >> 5;
  for (int kt = 0; kt < nk; ++kt) {
    const int k0 = kt << 5;
    if constexpr (AT) {
#pragma unroll
      for (int it = 0; it < BM / 64; ++it) {
        const int c = tid + 256 * it;
        const int kp = c & 15;
        const int lq = (c >> 4) * 4;
        const int mrow = m0 + lq;
        const int bb = mrow / SL;
        const size_t rowo = (size_t)(bb * K + k0 + 2 * kp) * SL + (mrow - bb * SL);
        const float4 v0 = *(const float4*)&Afp[rowo];
        const float4 v1 = *(const float4*)&Afp[rowo + SL];
        const float ve0[4] = {v0.x, v0.y, v0.z, v0.w};
        const float ve1[4] = {v1.x, v1.y, v1.z, v1.w};
#pragma unroll
        for (int e = 0; e < 4; ++e) {
          const unsigned int pk =
              (unsigned int)cvt_bf(ve0[e]) | ((unsigned int)cvt_bf(ve1[e]) << 16);
          *(unsigned int*)&As[(lq + e) * 40 + 2 * kp] = pk;
        }
      }
    } else {
#pragma unroll
      for (int it = 0; it < (BM * 4) / 256; ++it) {
        const int c = tid + 256 * it;
        const int row = c >> 2, ks = (c & 3) * 8;
        *(short8*)&As[row * 40 + ks] =
            *(const short8*)&A[(size_t)(m0 + row) * K + k0 + ks];
      }
    }
#pragma unroll
    for (int it = 0; it < (BN * 8) / 256; ++it) {
      const int c = tid + 256 * it;
      const int row = c >> 3, ks = (c & 7) * 4;
      float4 v = make_float4(0.f, 0.f, 0.f, 0.f);
      if (!NMASK || (n0 + row) < NCAP)
        v = *(const float4*)&W[(size_t)(n0 + row) * K + k0 + ks];
      short4v o4;
      o4[0] = (short)cvt_bf(v.x);
      o4[1] = (short)cvt_bf(v.y);
      o4[2] = (short)cvt_bf(v.z);
      o4[3] = (short)cvt_bf(v.w);
      *(short4v*)&Bs[row * 40 + ks] = o4;
    }
    __syncthreads();
    short8 af[FM], bfv[FN];
#pragma unroll
    for (int i = 0; i < FM; ++i)
      af[i] = *(const short8*)&As[(wm * WM + i * 16 + r16) * 40 + kg];
#pragma unroll
    for (int j = 0; j < FN; ++j)
      bfv[j] = *(const short8*)&Bs[(wn * WN + j * 16 + r16) * 40 + kg];
#pragma unroll
    for (int i = 0; i < FM; ++i)
#pragma unroll
      for (int j = 0; j < FN; ++j)
        acc[i][j] = __builtin_amdgcn_mfma_f32_16x16x32_bf16(af[i], bfv[j],
                                                            acc[i][j], 0, 0, 0);
    __syncthreads();
  }

#pragma unroll
  for (int i = 0; i < FM; ++i) {
#pragma unroll
    for (int j = 0; j < FN; ++j) {
      const int n = n0 + wn * WN + j * 16 + r16;
      const int mb = m0 + wm * WM + i * 16 + ((lane >> 4) << 2);
      f32x4 a = acc[i][j];
      if (MEPI == 0) {
        if (n < DR) {
#pragma unroll
          for (int r = 0; r < 4; ++r) out[(size_t)(mb + r) * DR + n] = a[r];
        } else if (n < NCAP) {
#pragma unroll
          for (int r = 0; r < 4; ++r) out2[(size_t)(mb + r) * 32 + (n - DR)] = a[r];
        }
      } else if (MEPI == 1) {
        float* base = out;
        int nn = n;
        if (n >= DI) { base = out2; nn = n - DI; }
        const int bb = mb / SL;
        const int ll = mb - bb * SL;
        *(f32x4*)&base[((size_t)(bb * DI + nn)) * SL + ll] = a;
      } else {  // MEPI 2
#pragma unroll
        for (int r = 0; r < 4; ++r) {
          const size_t off = (size_t)(mb + r) * DM + n;
          const float nv = out[off] + a[r];
          out[off] = nv;
          outb[off] = cvt_bf(nv);
        }
      }
    }
  }
}

// ---------------- fp32 SIMT GEMM (dt_proj, K=24) ----------------
template <int EPI, bool KTAIL, int NCAP>
__global__ __launch_bounds__(256) void k_gemm(
    const float* __restrict__ A, const float* __restrict__ W,
    const float* __restrict__ bias, float* __restrict__ out, int K, int lda) {
  __shared__ float sm[4352];
  const int tid = threadIdx.x;
  const int m0 = blockIdx.x * 64;
  const int n0 = blockIdx.y * 64;
  const int b = m0 / SL, l0 = m0 % SL;
  const int tm = tid >> 4, tn = tid & 15;
  float acc[4][4] = {};
  float* As = sm;
  float* Ws = sm + 16 * 68;

  const int nk = (K + 15) / 16;
  for (int kt = 0; kt < nk; ++kt) {
    const int k0 = kt * 16;
    {
      const int row = tid >> 2;
      const int kq = (tid & 3) * 4;
      const int kb = k0 + kq;
      float4 v = make_float4(0.f, 0.f, 0.f, 0.f);
      if (!KTAIL || kb < K) v = *(const float4*)&A[(size_t)(m0 + row) * lda + kb];
      As[(kq + 0) * 68 + row] = v.x;
      As[(kq + 1) * 68 + row] = v.y;
      As[(kq + 2) * 68 + row] = v.z;
      As[(kq + 3) * 68 + row] = v.w;
    }
    {
      const int row = tid >> 2;
      const int kq = (tid & 3) * 4;
      const int kb = k0 + kq;
      float4 v = make_float4(0.f, 0.f, 0.f, 0.f);
      const bool nok = (NCAP % 64 == 0) || (n0 + row < NCAP);
      if (nok && (!KTAIL || kb < K)) v = *(const float4*)&W[(size_t)(n0 + row) * K + kb];
      Ws[(kq + 0) * 68 + row] = v.x;
      Ws[(kq + 1) * 68 + row] = v.y;
      Ws[(kq + 2) * 68 + row] = v.z;
      Ws[(kq + 3) * 68 + row] = v.w;
    }
    __syncthreads();
#pragma unroll
    for (int kk = 0; kk < 16; ++kk) {
      const float4 av = *(const float4*)&As[kk * 68 + 4 * tm];
      const float4 wv = *(const float4*)&Ws[kk * 68 + 4 * tn];
      const float ax[4] = {av.x, av.y, av.z, av.w};
      const float wx[4] = {wv.x, wv.y, wv.z, wv.w};
#pragma unroll
      for (int i = 0; i < 4; ++i)
#pragma unroll
        for (int j = 0; j < 4; ++j) acc[i][j] = fmaf(ax[i], wx[j], acc[i][j]);
    }
    __syncthreads();
  }

#pragma unroll
  for (int j = 0; j < 4; ++j) {
    const int nn = 4 * tn + j;
#pragma unroll
    for (int i = 0; i < 4; ++i) {
      float v = acc[i][j];
      if (EPI == 2) v = softplusf(v + bias[n0 + nn]);
      sm[nn * 68 + 4 * tm + i] = v;
    }
  }
  __syncthreads();
  const int row = tid >> 2;
  const int seg = (tid & 3) * 16;
  const float* src = &sm[row * 68 + seg];
  float* dst = out + ((size_t)(b * DI + n0 + row)) * SL + l0 + seg;
#pragma unroll
  for (int q = 0; q < 4; ++q) {
    *(float4*)&dst[q * 4] = *(const float4*)&src[q * 4];
  }
}

// ---------------- depthwise causal conv1d + bias + silu (4 l per thread) --------
__global__ void k_conv(const float* __restrict__ xcT, const float* __restrict__ cw,
                       const float* __restrict__ cb, float* __restrict__ uT) {
  const size_t idx = (size_t)blockIdx.x * 256 + threadIdx.x;
  const int l4 = (int)(idx % (SL / 4)) * 4;
  const int bd = (int)(idx / (SL / 4));
  const int d = bd % DI;
  const float* row = xcT + (size_t)bd * SL;
  const float4 w = *(const float4*)&cw[d * 4];
  const float4 cur = *(const float4*)&row[l4];
  float p1 = 0.f, p2 = 0.f, p3 = 0.f;
  if (l4 > 0) {
    const float4 pv = *(const float4*)&row[l4 - 4];
    p1 = pv.y; p2 = pv.z; p3 = pv.w;
  }
  const float cbd = cb[d];
  float4 o;
  o.x = cbd + w.w * cur.x + w.z * p3 + w.y * p2 + w.x * p1;
  o.y = cbd + w.w * cur.y + w.z * cur.x + w.y * p3 + w.x * p2;
  o.z = cbd + w.w * cur.z + w.z * cur.y + w.y * cur.x + w.x * p3;
  o.w = cbd + w.w * cur.w + w.z * cur.z + w.y * cur.y + w.x * cur.x;
  o.x = siluf(o.x); o.y = siluf(o.y); o.z = siluf(o.z); o.w = siluf(o.w);
  *(float4*)&uT[(size_t)bd * SL + l4] = o;
}

// ---------------- wave-synchronous fused selective scan -----------------------
__global__ __launch_bounds__(256) void k_scanw(
    const float* __restrict__ deltaT, const float* __restrict__ uT,
    const float* __restrict__ BC, const float* __restrict__ resT,
    const float* __restrict__ A_log, const float* __restrict__ Dp,
    float* __restrict__ yT) {
  const int tid = threadIdx.x;
  const int lane = tid & 63, wv = tid >> 6;
  const int n = lane & 15, g = lane >> 4;
  const int chain = blockIdx.x * 4 + wv;
  const int b = chain / DI, d = chain % DI;
  const float a2 = -expf(A_log[d * DSN + n]) * 1.44269504088896341f;
  const float dp = Dp[d];
  const float* drow = deltaT + (size_t)chain * SL;
  const float* urow = uT + (size_t)chain * SL;
  const float* resr = resT + (size_t)chain * SL;
  const float* bcb = BC + (size_t)b * SL * 32;
  float* yr = yT + (size_t)chain * SL;
  float carry = 0.f;
  const bool b0 = n & 1, b1 = (n >> 1) & 1, b2 = (n >> 2) & 1, b3 = (n >> 3) & 1;

  for (int tb = 0; tb < SL; tb += 64) {
    const int l0 = tb + g * 16;
    float da[16], dbu[16];
    float h = 0.f, dsum = 0.f;
#pragma unroll
    for (int k = 0; k < 16; ++k) {
      const float dl = drow[l0 + k];
      const float ul = urow[l0 + k];
      const float Bv = bcb[(size_t)(l0 + k) * 32 + n];
      const float e = exp2f(dl * a2);
      da[k] = e;
      dbu[k] = dl * ul * Bv;
      h = fmaf(e, h, dbu[k]);
      dsum += dl;
    }
    float Aagg = exp2f(a2 * dsum);
    float Bagg = h;
#pragma unroll
    for (int off = 16; off <= 32; off <<= 1) {
      const float Ae = __shfl(Aagg, (lane - off) & 63);
      const float Be = __shfl(Bagg, (lane - off) & 63);
      if (lane >= off) {
        Bagg = fmaf(Aagg, Be, Bagg);
        Aagg *= Ae;
      }
    }
    const float Pa = __shfl(Aagg, (lane - 16) & 63);
    const float Pb = __shfl(Bagg, (lane - 16) & 63);
    const float hstart = (g == 0) ? carry : fmaf(Pa, carry, Pb);
    const float cA = __shfl(Aagg, 48 | n);
    const float cB = __shfl(Bagg, 48 | n);
    float p[16];
    h = hstart;
#pragma unroll
    for (int k = 0; k < 16; ++k) {
      h = fmaf(da[k], h, dbu[k]);
      p[k] = h * bcb[(size_t)(l0 + k) * 32 + 16 + n];
    }
    carry = fmaf(cA, carry, cB);
    // stream-merging reduction over the 16 state lanes
    float q8[8];
#pragma unroll
    for (int i = 0; i < 8; ++i) {
      const float mine = b0 ? p[2 * i + 1] : p[2 * i];
      const float oth = b0 ? p[2 * i] : p[2 * i + 1];
      q8[i] = mine + __shfl_xor(oth, 1);
    }
    float q4[4];
#pragma unroll
    for (int i = 0; i < 4; ++i) {
      const float mine = b1 ? q8[2 * i + 1] : q8[2 * i];
      const float oth = b1 ? q8[2 * i] : q8[2 * i + 1];
      q4[i] = mine + __shfl_xor(oth, 2);
    }
    float q2[2];
#pragma unroll
    for (int i = 0; i < 2; ++i) {
      const float mine = b2 ? q4[2 * i + 1] : q4[2 * i];
      const float oth = b2 ? q4[2 * i] : q4[2 * i + 1];
      q2[i] = mine + __shfl_xor(oth, 4);
    }
    const float mine = b3 ? q2[1] : q2[0];
    const float oth = b3 ? q2[0] : q2[1];
    const float ysum = mine + __shfl_xor(oth, 8);
    const float ul = urow[l0 + n];
    const float r = resr[l0 + n];
    yr[l0 + n] = (ysum + ul * dp) * siluf(r);
  }
}

// ---------------- RMS denom ----------------
__global__ void k_rinv(const float* __restrict__ t, float* __restrict__ rinv) {
  const int row = blockIdx.x;
  const float* tr = t + (size_t)row * DM;
  const int tid = threadIdx.x;
  float ss = 0.f;
#pragma unroll
  for (int k = 0; k < DM / 64; ++k) {
    const float v = tr[tid + k * 64];
    ss = fmaf(v, v, ss);
  }
  ss += __shfl_xor(ss, 1);
  ss += __shfl_xor(ss, 2);
  ss += __shfl_xor(ss, 4);
  ss += __shfl_xor(ss, 8);
  ss += __shfl_xor(ss, 16);
  ss += __shfl_xor(ss, 32);
  if (tid == 0) rinv[row] = 1.f / sqrtf(ss / DM + 1e-5f);
}

// ---------------- pooled partial sums ----------------
__global__ void k_pool(const float* __restrict__ t, const float* __restrict__ rinv,
                       float* __restrict__ part) {
  const int b = blockIdx.x, dmb = blockIdx.y, ch = blockIdx.z;
  const int dm = dmb * 64 + threadIdx.x;
  const int lbeg = ch * (SL / 32);
  float s = 0.f;
  for (int l = lbeg; l < lbeg + SL / 32; ++l)
    s = fmaf(t[((size_t)b * SL + l) * DM + dm], rinv[b * SL + l], s);
  part[((size_t)ch * NB + b) * DM + dm] = s;
}

// ---------------- head ----------------
__global__ void k_head(const float* __restrict__ part, const float* __restrict__ norm_w,
                       const float* __restrict__ hw, const float* __restrict__ hb,
                       float* __restrict__ out) {
  const int b = blockIdx.x;
  const int tid = threadIdx.x;
  __shared__ float pv[DM];
  for (int k = tid; k < DM; k += 64) {
    float s = 0.f;
#pragma unroll
    for (int c = 0; c < 32; ++c) s += part[((size_t)c * NB + b) * DM + k];
    pv[k] = s * norm_w[k] * (1.f / SL);
  }
  __syncthreads();
  const int cls = blockIdx.y * 64 + tid;
  if (cls < NCLS) {
    const float* wr = hw + (size_t)cls * DM;
    float acc = hb[cls];
#pragma unroll 4
    for (int k = 0; k < DM; k += 4) {
      const float4 w4 = *(const float4*)&wr[k];
      acc = fmaf(pv[k], w4.x, acc);
      acc = fmaf(pv[k + 1], w4.y, acc);
      acc = fmaf(pv[k + 2], w4.z, acc);
      acc = fmaf(pv[k + 3], w4.w, acc);
    }
    out[(size_t)b * NCLS + cls] = acc;
  }
}

extern "C" void kernel_launch(void* const* d_in, const int* in_sizes, int n_in,
                              void* d_out, int out_size, void* d_ws, size_t ws_size,
                              hipStream_t stream) {
  (void)in_sizes; (void)n_in; (void)out_size; (void)ws_size;
  const float* x = (const float*)d_in[0];
  const float* patch_w = (const float*)d_in[1];
  const float* patch_b = (const float*)d_in[2];
  const float* in_proj_w = (const float*)d_in[3];
  const float* conv_w = (const float*)d_in[4];
  const float* conv_b = (const float*)d_in[5];
  const float* x_proj_w = (const float*)d_in[6];
  const float* dt_proj_w = (const float*)d_in[7];
  const float* dt_proj_b = (const float*)d_in[8];
  const float* A_log = (const float*)d_in[9];
  const float* Dp = (const float*)d_in[10];
  const float* out_proj_w = (const float*)d_in[11];
  const float* norm_w = (const float*)d_in[12];
  const float* head_w = (const float*)d_in[13];
  const float* head_b = (const float*)d_in[14];

  float* ws = (float*)d_ws;
  size_t o = 0;
  float* t = ws + o;     o += (size_t)NB * SL * DM;
  float* xcT = ws + o;   o += (size_t)NB * DI * SL;
  float* resT = ws + o;  o += (size_t)NB * DI * SL;
  float* uT = ws + o;    o += (size_t)NB * DI * SL;
  float* dltT = ws + o;  o += (size_t)NB * DI * SL;
  float* yT = ws + o;    o += (size_t)NB * DI * SL;
  float* dbl24 = ws + o; o += (size_t)NB * SL * DR;
  float* BC = ws + o;    o += (size_t)NB * SL * 32;
  float* rinv = ws + o;  o += (size_t)NB * SL;
  float* part = ws + o;  o += (size_t)32 * NB * DM;
  unsigned short* tb = (unsigned short*)(ws + o); o += (size_t)NB * SL * DM / 2;

  k_patch<<<(NB * SL) / PTOK, 128, 0, stream>>>(x, patch_w, patch_b, t, tb);

  for (int i = 0; i < NLAYER; ++i) {
    // in_proj: tb[M,384](bf16) x W[1536,384]^T -> xcT / resT ([b][n][l] fp32)
    k_mgemm<128, 128, 1, 1536, false><<<dim3(98, 12), 256, 0, stream>>>(
        tb, nullptr, in_proj_w + (size_t)i * 2 * DI * DM, xcT, resT, nullptr, DM);
    // depthwise causal conv + silu -> uT
    k_conv<<<(NB * DI * SL / 4) / 256, 256, 0, stream>>>(
        xcT, conv_w + (size_t)i * DI * 4, conv_b + (size_t)i * DI, uT);
    // x_proj: uT (AT-staged bf16) x W[56,768]^T -> dbl24 + BC[b][l][32]
    k_mgemm<64, 64, 0, XPN, true><<<dim3(196, 1), 256, 0, stream>>>(
        nullptr, uT, x_proj_w + (size_t)i * XPN * DI, dbl24, BC, nullptr, DI);
    // dt_proj (fp32 SIMT): softplus(dbl24 @ dt_w^T + b) -> dltT [b][d][l]
    k_gemm<2, true, 64><<<dim3(196, 12), 256, 0, stream>>>(
        dbl24, dt_proj_w + (size_t)i * DI * DR, dt_proj_b + (size_t)i * DI, dltT,
        DR, DR);
    // wave-synchronous fused selective scan + gate -> yT
    k_scanw<<<NCHAIN / 4, 256, 0, stream>>>(
        dltT, uT, BC, resT, A_log + (size_t)i * DI * DSN, Dp + (size_t)i * DI, yT);
    // out_proj: yT (AT-staged bf16) x W[384,768]^T -> t += ; tb = bf16(t)
    k_mgemm<128, 128, 2, 384, true><<<dim3(98, 3), 256, 0, stream>>>(
        nullptr, yT, out_proj_w + (size_t)i * DM * DI, t, nullptr, tb, DI);
  }

  k_rinv<<<NB * SL, 64, 0, stream>>>(t, rinv);
  k_pool<<<dim3(NB, DM / 64, 32), 64, 0, stream>>>(t, rinv, part);
  k_head<<<dim3(NB, 16), 64, 0, stream>>>(part, norm_w, head_w, head_b, (float*)d_out);
}

// Round 11
// 1175.774 us; speedup vs baseline: 1.6974x; 1.6974x over previous
//
#include <hip/hip_runtime.h>
#include <math.h>

// CausalVisionMamba — round 11: fix k_patch register spill (unroll-1 outer dm
// loop, 8-token accumulator chunks). Everything else = round 9/10 pipeline.

namespace {
constexpr int NB = 4;
constexpr int SL = 3136;
constexpr int DM = 384;
constexpr int DI = 768;
constexpr int DSN = 16;
constexpr int DR = 24;
constexpr int NLAYER = 4;
constexpr int NCLS = 1000;
constexpr int XPN = DR + 2 * DSN;  // 56
constexpr int NCHAIN = NB * DI;    // 3072
constexpr int PTOK = 32;           // tokens per patch-embed block
}

typedef float f32x4 __attribute__((ext_vector_type(4)));
typedef short short8 __attribute__((ext_vector_type(8)));
typedef short short4v __attribute__((ext_vector_type(4)));

__device__ __forceinline__ float siluf(float x) { return x / (1.f + expf(-x)); }
__device__ __forceinline__ float softplusf(float x) {
  return fmaxf(x, 0.f) + log1pf(expf(-fabsf(x)));
}
__device__ __forceinline__ unsigned short cvt_bf(float f) {
  unsigned int x = __float_as_uint(f);
  unsigned int r = (x + 0x7fffu + ((x >> 16) & 1u)) >> 16;  // RNE
  return (unsigned short)r;
}

// ---------------- patch embed: t[b][l][dm] fp32 + tb bf16 ----------------
// 32 tokens/block, 128 threads. One weight-row cache (12 float4) live at a
// time (#pragma unroll 1); tokens processed in 8-wide accumulator chunks.
__global__ __launch_bounds__(128) void k_patch(
    const float* __restrict__ x, const float* __restrict__ w,
    const float* __restrict__ bias, float* __restrict__ t,
    unsigned short* __restrict__ tb) {
  __shared__ float patch[PTOK][48];
  const int tid = threadIdx.x;
  const int m0 = blockIdx.x * PTOK;
  const int b = m0 / SL, lbase = m0 % SL;
  // im2col: 32 tokens x 12 float4 chunks = 384 chunks, 3 per thread
#pragma unroll
  for (int i = 0; i < 3; ++i) {
    const int c = tid + i * 128;
    const int tok = c / 12, r = c % 12;
    const int ch = r >> 2, kh = r & 3;
    const int l = lbase + tok;
    const int hh = l / 56, ww = l % 56;
    const float4 v =
        *(const float4*)&x[((size_t)(b * 3 + ch) * 224 + (hh * 4 + kh)) * 224 + ww * 4];
    *(float4*)&patch[tok][ch * 16 + kh * 4] = v;
  }
  __syncthreads();
#pragma unroll 1
  for (int i = 0; i < 3; ++i) {
    const int dm = tid + i * 128;
    float4 wr[12];
    const float4* w4 = (const float4*)(w + (size_t)dm * 48);
#pragma unroll
    for (int q = 0; q < 12; ++q) wr[q] = w4[q];
    const float bv = bias[dm];
#pragma unroll 1
    for (int tok0 = 0; tok0 < PTOK; tok0 += 8) {
      float acc[8];
#pragma unroll
      for (int j = 0; j < 8; ++j) acc[j] = bv;
#pragma unroll
      for (int q = 0; q < 12; ++q) {
        const float4 wv = wr[q];
#pragma unroll
        for (int j = 0; j < 8; ++j) {
          const float4 pv = *(const float4*)&patch[tok0 + j][q * 4];
          acc[j] = fmaf(pv.x, wv.x, acc[j]);
          acc[j] = fmaf(pv.y, wv.y, acc[j]);
          acc[j] = fmaf(pv.z, wv.z, acc[j]);
          acc[j] = fmaf(pv.w, wv.w, acc[j]);
        }
      }
#pragma unroll
      for (int j = 0; j < 8; ++j) {
        const size_t o = ((size_t)(m0 + tok0 + j)) * DM + dm;
        t[o] = acc[j];
        tb[o] = cvt_bf(acc[j]);
      }
    }
  }
}

// ---------------- bf16 MFMA GEMM: D = A[M,K](bf16) * W[N,K]^T(fp32->bf16) -------
template <int BM, int BN, int MEPI, int NCAP, bool AT>
__global__ __launch_bounds__(256) void k_mgemm(
    const unsigned short* __restrict__ A, const float* __restrict__ Afp,
    const float* __restrict__ W, float* __restrict__ out,
    float* __restrict__ out2, unsigned short* __restrict__ outb, const int K) {
  constexpr int WM = BM / 2, WN = BN / 2, FM = WM / 16, FN = WN / 16;
  constexpr bool NMASK = (NCAP % BN) != 0;
  __shared__ unsigned short As[BM * 40];
  __shared__ unsigned short Bs[BN * 40];
  const int tid = threadIdx.x;
  const int lane = tid & 63, wave = tid >> 6;
  const int wm = wave >> 1, wn = wave & 1;
  const int m0 = blockIdx.x * BM, n0 = blockIdx.y * BN;
  const int r16 = lane & 15, kg = (lane >> 4) * 8;
  f32x4 acc[FM][FN] = {};
  const int nk = K >> 5;
  for (int kt = 0; kt < nk; ++kt) {
    const int k0 = kt << 5;
    if constexpr (AT) {
#pragma unroll
      for (int it = 0; it < BM / 64; ++it) {
        const int c = tid + 256 * it;
        const int kp = c & 15;
        const int lq = (c >> 4) * 4;
        const int mrow = m0 + lq;
        const int bb = mrow / SL;
        const size_t rowo = (size_t)(bb * K + k0 + 2 * kp) * SL + (mrow - bb * SL);
        const float4 v0 = *(const float4*)&Afp[rowo];
        const float4 v1 = *(const float4*)&Afp[rowo + SL];
        const float ve0[4] = {v0.x, v0.y, v0.z, v0.w};
        const float ve1[4] = {v1.x, v1.y, v1.z, v1.w};
#pragma unroll
        for (int e = 0; e < 4; ++e) {
          const unsigned int pk =
              (unsigned int)cvt_bf(ve0[e]) | ((unsigned int)cvt_bf(ve1[e]) << 16);
          *(unsigned int*)&As[(lq + e) * 40 + 2 * kp] = pk;
        }
      }
    } else {
#pragma unroll
      for (int it = 0; it < (BM * 4) / 256; ++it) {
        const int c = tid + 256 * it;
        const int row = c >> 2, ks = (c & 3) * 8;
        *(short8*)&As[row * 40 + ks] =
            *(const short8*)&A[(size_t)(m0 + row) * K + k0 + ks];
      }
    }
#pragma unroll
    for (int it = 0; it < (BN * 8) / 256; ++it) {
      const int c = tid + 256 * it;
      const int row = c >> 3, ks = (c & 7) * 4;
      float4 v = make_float4(0.f, 0.f, 0.f, 0.f);
      if (!NMASK || (n0 + row) < NCAP)
        v = *(const float4*)&W[(size_t)(n0 + row) * K + k0 + ks];
      short4v o4;
      o4[0] = (short)cvt_bf(v.x);
      o4[1] = (short)cvt_bf(v.y);
      o4[2] = (short)cvt_bf(v.z);
      o4[3] = (short)cvt_bf(v.w);
      *(short4v*)&Bs[row * 40 + ks] = o4;
    }
    __syncthreads();
    short8 af[FM], bfv[FN];
#pragma unroll
    for (int i = 0; i < FM; ++i)
      af[i] = *(const short8*)&As[(wm * WM + i * 16 + r16) * 40 + kg];
#pragma unroll
    for (int j = 0; j < FN; ++j)
      bfv[j] = *(const short8*)&Bs[(wn * WN + j * 16 + r16) * 40 + kg];
#pragma unroll
    for (int i = 0; i < FM; ++i)
#pragma unroll
      for (int j = 0; j < FN; ++j)
        acc[i][j] = __builtin_amdgcn_mfma_f32_16x16x32_bf16(af[i], bfv[j],
                                                            acc[i][j], 0, 0, 0);
    __syncthreads();
  }

#pragma unroll
  for (int i = 0; i < FM; ++i) {
#pragma unroll
    for (int j = 0; j < FN; ++j) {
      const int n = n0 + wn * WN + j * 16 + r16;
      const int mb = m0 + wm * WM + i * 16 + ((lane >> 4) << 2);
      f32x4 a = acc[i][j];
      if (MEPI == 0) {
        if (n < DR) {
#pragma unroll
          for (int r = 0; r < 4; ++r) out[(size_t)(mb + r) * DR + n] = a[r];
        } else if (n < NCAP) {
#pragma unroll
          for (int r = 0; r < 4; ++r) out2[(size_t)(mb + r) * 32 + (n - DR)] = a[r];
        }
      } else if (MEPI == 1) {
        float* base = out;
        int nn = n;
        if (n >= DI) { base = out2; nn = n - DI; }
        const int bb = mb / SL;
        const int ll = mb - bb * SL;
        *(f32x4*)&base[((size_t)(bb * DI + nn)) * SL + ll] = a;
      } else {  // MEPI 2
#pragma unroll
        for (int r = 0; r < 4; ++r) {
          const size_t off = (size_t)(mb + r) * DM + n;
          const float nv = out[off] + a[r];
          out[off] = nv;
          outb[off] = cvt_bf(nv);
        }
      }
    }
  }
}

// ---------------- fp32 SIMT GEMM (dt_proj, K=24) ----------------
template <int EPI, bool KTAIL, int NCAP>
__global__ __launch_bounds__(256) void k_gemm(
    const float* __restrict__ A, const float* __restrict__ W,
    const float* __restrict__ bias, float* __restrict__ out, int K, int lda) {
  __shared__ float sm[4352];
  const int tid = threadIdx.x;
  const int m0 = blockIdx.x * 64;
  const int n0 = blockIdx.y * 64;
  const int b = m0 / SL, l0 = m0 % SL;
  const int tm = tid >> 4, tn = tid & 15;
  float acc[4][4] = {};
  float* As = sm;
  float* Ws = sm + 16 * 68;

  const int nk = (K + 15) / 16;
  for (int kt = 0; kt < nk; ++kt) {
    const int k0 = kt * 16;
    {
      const int row = tid >> 2;
      const int kq = (tid & 3) * 4;
      const int kb = k0 + kq;
      float4 v = make_float4(0.f, 0.f, 0.f, 0.f);
      if (!KTAIL || kb < K) v = *(const float4*)&A[(size_t)(m0 + row) * lda + kb];
      As[(kq + 0) * 68 + row] = v.x;
      As[(kq + 1) * 68 + row] = v.y;
      As[(kq + 2) * 68 + row] = v.z;
      As[(kq + 3) * 68 + row] = v.w;
    }
    {
      const int row = tid >> 2;
      const int kq = (tid & 3) * 4;
      const int kb = k0 + kq;
      float4 v = make_float4(0.f, 0.f, 0.f, 0.f);
      const bool nok = (NCAP % 64 == 0) || (n0 + row < NCAP);
      if (nok && (!KTAIL || kb < K)) v = *(const float4*)&W[(size_t)(n0 + row) * K + kb];
      Ws[(kq + 0) * 68 + row] = v.x;
      Ws[(kq + 1) * 68 + row] = v.y;
      Ws[(kq + 2) * 68 + row] = v.z;
      Ws[(kq + 3) * 68 + row] = v.w;
    }
    __syncthreads();
#pragma unroll
    for (int kk = 0; kk < 16; ++kk) {
      const float4 av = *(const float4*)&As[kk * 68 + 4 * tm];
      const float4 wv = *(const float4*)&Ws[kk * 68 + 4 * tn];
      const float ax[4] = {av.x, av.y, av.z, av.w};
      const float wx[4] = {wv.x, wv.y, wv.z, wv.w};
#pragma unroll
      for (int i = 0; i < 4; ++i)
#pragma unroll
        for (int j = 0; j < 4; ++j) acc[i][j] = fmaf(ax[i], wx[j], acc[i][j]);
    }
    __syncthreads();
  }

#pragma unroll
  for (int j = 0; j < 4; ++j) {
    const int nn = 4 * tn + j;
#pragma unroll
    for (int i = 0; i < 4; ++i) {
      float v = acc[i][j];
      if (EPI == 2) v = softplusf(v + bias[n0 + nn]);
      sm[nn * 68 + 4 * tm + i] = v;
    }
  }
  __syncthreads();
  const int row = tid >> 2;
  const int seg = (tid & 3) * 16;
  const float* src = &sm[row * 68 + seg];
  float* dst = out + ((size_t)(b * DI + n0 + row)) * SL + l0 + seg;
#pragma unroll
  for (int q = 0; q < 4; ++q) {
    *(float4*)&dst[q * 4] = *(const float4*)&src[q * 4];
  }
}

// ---------------- depthwise causal conv1d + bias + silu (4 l per thread) --------
__global__ void k_conv(const float* __restrict__ xcT, const float* __restrict__ cw,
                       const float* __restrict__ cb, float* __restrict__ uT) {
  const size_t idx = (size_t)blockIdx.x * 256 + threadIdx.x;
  const int l4 = (int)(idx % (SL / 4)) * 4;
  const int bd = (int)(idx / (SL / 4));
  const int d = bd % DI;
  const float* row = xcT + (size_t)bd * SL;
  const float4 w = *(const float4*)&cw[d * 4];
  const float4 cur = *(const float4*)&row[l4];
  float p1 = 0.f, p2 = 0.f, p3 = 0.f;
  if (l4 > 0) {
    const float4 pv = *(const float4*)&row[l4 - 4];
    p1 = pv.y; p2 = pv.z; p3 = pv.w;
  }
  const float cbd = cb[d];
  float4 o;
  o.x = cbd + w.w * cur.x + w.z * p3 + w.y * p2 + w.x * p1;
  o.y = cbd + w.w * cur.y + w.z * cur.x + w.y * p3 + w.x * p2;
  o.z = cbd + w.w * cur.z + w.z * cur.y + w.y * cur.x + w.x * p3;
  o.w = cbd + w.w * cur.w + w.z * cur.z + w.y * cur.y + w.x * cur.x;
  o.x = siluf(o.x); o.y = siluf(o.y); o.z = siluf(o.z); o.w = siluf(o.w);
  *(float4*)&uT[(size_t)bd * SL + l4] = o;
}

// ---------------- wave-synchronous fused selective scan -----------------------
__global__ __launch_bounds__(256) void k_scanw(
    const float* __restrict__ deltaT, const float* __restrict__ uT,
    const float* __restrict__ BC, const float* __restrict__ resT,
    const float* __restrict__ A_log, const float* __restrict__ Dp,
    float* __restrict__ yT) {
  const int tid = threadIdx.x;
  const int lane = tid & 63, wv = tid >> 6;
  const int n = lane & 15, g = lane >> 4;
  const int chain = blockIdx.x * 4 + wv;
  const int b = chain / DI, d = chain % DI;
  const float a2 = -expf(A_log[d * DSN + n]) * 1.44269504088896341f;
  const float dp = Dp[d];
  const float* drow = deltaT + (size_t)chain * SL;
  const float* urow = uT + (size_t)chain * SL;
  const float* resr = resT + (size_t)chain * SL;
  const float* bcb = BC + (size_t)b * SL * 32;
  float* yr = yT + (size_t)chain * SL;
  float carry = 0.f;
  const bool b0 = n & 1, b1 = (n >> 1) & 1, b2 = (n >> 2) & 1, b3 = (n >> 3) & 1;

  for (int tb = 0; tb < SL; tb += 64) {
    const int l0 = tb + g * 16;
    float da[16], dbu[16];
    float h = 0.f, dsum = 0.f;
#pragma unroll
    for (int k = 0; k < 16; ++k) {
      const float dl = drow[l0 + k];
      const float ul = urow[l0 + k];
      const float Bv = bcb[(size_t)(l0 + k) * 32 + n];
      const float e = exp2f(dl * a2);
      da[k] = e;
      dbu[k] = dl * ul * Bv;
      h = fmaf(e, h, dbu[k]);
      dsum += dl;
    }
    float Aagg = exp2f(a2 * dsum);
    float Bagg = h;
#pragma unroll
    for (int off = 16; off <= 32; off <<= 1) {
      const float Ae = __shfl(Aagg, (lane - off) & 63);
      const float Be = __shfl(Bagg, (lane - off) & 63);
      if (lane >= off) {
        Bagg = fmaf(Aagg, Be, Bagg);
        Aagg *= Ae;
      }
    }
    const float Pa = __shfl(Aagg, (lane - 16) & 63);
    const float Pb = __shfl(Bagg, (lane - 16) & 63);
    const float hstart = (g == 0) ? carry : fmaf(Pa, carry, Pb);
    const float cA = __shfl(Aagg, 48 | n);
    const float cB = __shfl(Bagg, 48 | n);
    float p[16];
    h = hstart;
#pragma unroll
    for (int k = 0; k < 16; ++k) {
      h = fmaf(da[k], h, dbu[k]);
      p[k] = h * bcb[(size_t)(l0 + k) * 32 + 16 + n];
    }
    carry = fmaf(cA, carry, cB);
    // stream-merging reduction over the 16 state lanes
    float q8[8];
#pragma unroll
    for (int i = 0; i < 8; ++i) {
      const float mine = b0 ? p[2 * i + 1] : p[2 * i];
      const float oth = b0 ? p[2 * i] : p[2 * i + 1];
      q8[i] = mine + __shfl_xor(oth, 1);
    }
    float q4[4];
#pragma unroll
    for (int i = 0; i < 4; ++i) {
      const float mine = b1 ? q8[2 * i + 1] : q8[2 * i];
      const float oth = b1 ? q8[2 * i] : q8[2 * i + 1];
      q4[i] = mine + __shfl_xor(oth, 2);
    }
    float q2[2];
#pragma unroll
    for (int i = 0; i < 2; ++i) {
      const float mine = b2 ? q4[2 * i + 1] : q4[2 * i];
      const float oth = b2 ? q4[2 * i] : q4[2 * i + 1];
      q2[i] = mine + __shfl_xor(oth, 4);
    }
    const float mine = b3 ? q2[1] : q2[0];
    const float oth = b3 ? q2[0] : q2[1];
    const float ysum = mine + __shfl_xor(oth, 8);
    const float ul = urow[l0 + n];
    const float r = resr[l0 + n];
    yr[l0 + n] = (ysum + ul * dp) * siluf(r);
  }
}

// ---------------- RMS denom ----------------
__global__ void k_rinv(const float* __restrict__ t, float* __restrict__ rinv) {
  const int row = blockIdx.x;
  const float* tr = t + (size_t)row * DM;
  const int tid = threadIdx.x;
  float ss = 0.f;
#pragma unroll
  for (int k = 0; k < DM / 64; ++k) {
    const float v = tr[tid + k * 64];
    ss = fmaf(v, v, ss);
  }
  ss += __shfl_xor(ss, 1);
  ss += __shfl_xor(ss, 2);
  ss += __shfl_xor(ss, 4);
  ss += __shfl_xor(ss, 8);
  ss += __shfl_xor(ss, 16);
  ss += __shfl_xor(ss, 32);
  if (tid == 0) rinv[row] = 1.f / sqrtf(ss / DM + 1e-5f);
}

// ---------------- pooled partial sums ----------------
__global__ void k_pool(const float* __restrict__ t, const float* __restrict__ rinv,
                       float* __restrict__ part) {
  const int b = blockIdx.x, dmb = blockIdx.y, ch = blockIdx.z;
  const int dm = dmb * 64 + threadIdx.x;
  const int lbeg = ch * (SL / 32);
  float s = 0.f;
  for (int l = lbeg; l < lbeg + SL / 32; ++l)
    s = fmaf(t[((size_t)b * SL + l) * DM + dm], rinv[b * SL + l], s);
  part[((size_t)ch * NB + b) * DM + dm] = s;
}

// ---------------- head ----------------
__global__ void k_head(const float* __restrict__ part, const float* __restrict__ norm_w,
                       const float* __restrict__ hw, const float* __restrict__ hb,
                       float* __restrict__ out) {
  const int b = blockIdx.x;
  const int tid = threadIdx.x;
  __shared__ float pv[DM];
  for (int k = tid; k < DM; k += 64) {
    float s = 0.f;
#pragma unroll
    for (int c = 0; c < 32; ++c) s += part[((size_t)c * NB + b) * DM + k];
    pv[k] = s * norm_w[k] * (1.f / SL);
  }
  __syncthreads();
  const int cls = blockIdx.y * 64 + tid;
  if (cls < NCLS) {
    const float* wr = hw + (size_t)cls * DM;
    float acc = hb[cls];
#pragma unroll 4
    for (int k = 0; k < DM; k += 4) {
      const float4 w4 = *(const float4*)&wr[k];
      acc = fmaf(pv[k], w4.x, acc);
      acc = fmaf(pv[k + 1], w4.y, acc);
      acc = fmaf(pv[k + 2], w4.z, acc);
      acc = fmaf(pv[k + 3], w4.w, acc);
    }
    out[(size_t)b * NCLS + cls] = acc;
  }
}

extern "C" void kernel_launch(void* const* d_in, const int* in_sizes, int n_in,
                              void* d_out, int out_size, void* d_ws, size_t ws_size,
                              hipStream_t stream) {
  (void)in_sizes; (void)n_in; (void)out_size; (void)ws_size;
  const float* x = (const float*)d_in[0];
  const float* patch_w = (const float*)d_in[1];
  const float* patch_b = (const float*)d_in[2];
  const float* in_proj_w = (const float*)d_in[3];
  const float* conv_w = (const float*)d_in[4];
  const float* conv_b = (const float*)d_in[5];
  const float* x_proj_w = (const float*)d_in[6];
  const float* dt_proj_w = (const float*)d_in[7];
  const float* dt_proj_b = (const float*)d_in[8];
  const float* A_log = (const float*)d_in[9];
  const float* Dp = (const float*)d_in[10];
  const float* out_proj_w = (const float*)d_in[11];
  const float* norm_w = (const float*)d_in[12];
  const float* head_w = (const float*)d_in[13];
  const float* head_b = (const float*)d_in[14];

  float* ws = (float*)d_ws;
  size_t o = 0;
  float* t = ws + o;     o += (size_t)NB * SL * DM;
  float* xcT = ws + o;   o += (size_t)NB * DI * SL;
  float* resT = ws + o;  o += (size_t)NB * DI * SL;
  float* uT = ws + o;    o += (size_t)NB * DI * SL;
  float* dltT = ws + o;  o += (size_t)NB * DI * SL;
  float* yT = ws + o;    o += (size_t)NB * DI * SL;
  float* dbl24 = ws + o; o += (size_t)NB * SL * DR;
  float* BC = ws + o;    o += (size_t)NB * SL * 32;
  float* rinv = ws + o;  o += (size_t)NB * SL;
  float* part = ws + o;  o += (size_t)32 * NB * DM;
  unsigned short* tb = (unsigned short*)(ws + o); o += (size_t)NB * SL * DM / 2;

  k_patch<<<(NB * SL) / PTOK, 128, 0, stream>>>(x, patch_w, patch_b, t, tb);

  for (int i = 0; i < NLAYER; ++i) {
    // in_proj: tb[M,384](bf16) x W[1536,384]^T -> xcT / resT ([b][n][l] fp32)
    k_mgemm<128, 128, 1, 1536, false><<<dim3(98, 12), 256, 0, stream>>>(
        tb, nullptr, in_proj_w + (size_t)i * 2 * DI * DM, xcT, resT, nullptr, DM);
    // depthwise causal conv + silu -> uT
    k_conv<<<(NB * DI * SL / 4) / 256, 256, 0, stream>>>(
        xcT, conv_w + (size_t)i * DI * 4, conv_b + (size_t)i * DI, uT);
    // x_proj: uT (AT-staged bf16) x W[56,768]^T -> dbl24 + BC[b][l][32]
    k_mgemm<64, 64, 0, XPN, true><<<dim3(196, 1), 256, 0, stream>>>(
        nullptr, uT, x_proj_w + (size_t)i * XPN * DI, dbl24, BC, nullptr, DI);
    // dt_proj (fp32 SIMT): softplus(dbl24 @ dt_w^T + b) -> dltT [b][d][l]
    k_gemm<2, true, 64><<<dim3(196, 12), 256, 0, stream>>>(
        dbl24, dt_proj_w + (size_t)i * DI * DR, dt_proj_b + (size_t)i * DI, dltT,
        DR, DR);
    // wave-synchronous fused selective scan + gate -> yT
    k_scanw<<<NCHAIN / 4, 256, 0, stream>>>(
        dltT, uT, BC, resT, A_log + (size_t)i * DI * DSN, Dp + (size_t)i * DI, yT);
    // out_proj: yT (AT-staged bf16) x W[384,768]^T -> t += ; tb = bf16(t)
    k_mgemm<128, 128, 2, 384, true><<<dim3(98, 3), 256, 0, stream>>>(
        nullptr, yT, out_proj_w + (size_t)i * DM * DI, t, nullptr, tb, DI);
  }

  k_rinv<<<NB * SL, 64, 0, stream>>>(t, rinv);
  k_pool<<<dim3(NB, DM / 64, 32), 64, 0, stream>>>(t, rinv, part);
  k_head<<<dim3(NB, 16), 64, 0, stream>>>(part, norm_w, head_w, head_b, (float*)d_out);
}

// Round 12
// 1137.208 us; speedup vs baseline: 1.7549x; 1.0339x over previous
//
#include <hip/hip_runtime.h>
#include <math.h>

// CausalVisionMamba — round 12: bf16 intermediate streams (xcT/resT/uT/yT);
// delta + B/C stay fp32. Pipeline otherwise = round 11.

namespace {
constexpr int NB = 4;
constexpr int SL = 3136;
constexpr int DM = 384;
constexpr int DI = 768;
constexpr int DSN = 16;
constexpr int DR = 24;
constexpr int NLAYER = 4;
constexpr int NCLS = 1000;
constexpr int XPN = DR + 2 * DSN;  // 56
constexpr int NCHAIN = NB * DI;    // 3072
constexpr int PTOK = 32;
}

typedef float f32x4 __attribute__((ext_vector_type(4)));
typedef short short8 __attribute__((ext_vector_type(8)));
typedef short short4v __attribute__((ext_vector_type(4)));
typedef unsigned short us4 __attribute__((ext_vector_type(4)));

__device__ __forceinline__ float siluf(float x) { return x / (1.f + expf(-x)); }
__device__ __forceinline__ float softplusf(float x) {
  return fmaxf(x, 0.f) + log1pf(expf(-fabsf(x)));
}
__device__ __forceinline__ unsigned short cvt_bf(float f) {
  unsigned int x = __float_as_uint(f);
  unsigned int r = (x + 0x7fffu + ((x >> 16) & 1u)) >> 16;  // RNE
  return (unsigned short)r;
}
__device__ __forceinline__ float bf2f(unsigned short v) {
  return __uint_as_float((unsigned int)v << 16);
}

// ---------------- patch embed: t[b][l][dm] fp32 + tb bf16 ----------------
__global__ __launch_bounds__(128) void k_patch(
    const float* __restrict__ x, const float* __restrict__ w,
    const float* __restrict__ bias, float* __restrict__ t,
    unsigned short* __restrict__ tb) {
  __shared__ float patch[PTOK][48];
  const int tid = threadIdx.x;
  const int m0 = blockIdx.x * PTOK;
  const int b = m0 / SL, lbase = m0 % SL;
#pragma unroll
  for (int i = 0; i < 3; ++i) {
    const int c = tid + i * 128;
    const int tok = c / 12, r = c % 12;
    const int ch = r >> 2, kh = r & 3;
    const int l = lbase + tok;
    const int hh = l / 56, ww = l % 56;
    const float4 v =
        *(const float4*)&x[((size_t)(b * 3 + ch) * 224 + (hh * 4 + kh)) * 224 + ww * 4];
    *(float4*)&patch[tok][ch * 16 + kh * 4] = v;
  }
  __syncthreads();
#pragma unroll 1
  for (int i = 0; i < 3; ++i) {
    const int dm = tid + i * 128;
    float4 wr[12];
    const float4* w4 = (const float4*)(w + (size_t)dm * 48);
#pragma unroll
    for (int q = 0; q < 12; ++q) wr[q] = w4[q];
    const float bv = bias[dm];
#pragma unroll 1
    for (int tok0 = 0; tok0 < PTOK; tok0 += 8) {
      float acc[8];
#pragma unroll
      for (int j = 0; j < 8; ++j) acc[j] = bv;
#pragma unroll
      for (int q = 0; q < 12; ++q) {
        const float4 wv = wr[q];
#pragma unroll
        for (int j = 0; j < 8; ++j) {
          const float4 pv = *(const float4*)&patch[tok0 + j][q * 4];
          acc[j] = fmaf(pv.x, wv.x, acc[j]);
          acc[j] = fmaf(pv.y, wv.y, acc[j]);
          acc[j] = fmaf(pv.z, wv.z, acc[j]);
          acc[j] = fmaf(pv.w, wv.w, acc[j]);
        }
      }
#pragma unroll
      for (int j = 0; j < 8; ++j) {
        const size_t o = ((size_t)(m0 + tok0 + j)) * DM + dm;
        t[o] = acc[j];
        tb[o] = cvt_bf(acc[j]);
      }
    }
  }
}

// ---------------- bf16 MFMA GEMM: D = A[M,K](bf16) * W[N,K]^T(fp32->bf16) -------
// AT=false: A is bf16 [M][K] row-major.
// AT=true : Abf is bf16 [B][K][SL]; staged with fused transpose (no cvt).
// MEPI 0: x_proj  -> n<DR: out=dbl24[m][24] fp32; DR<=n<NCAP: out2=BC[m][32] fp32
// MEPI 1: in_proj -> bf16 stores: n<DI: out=xcT [b][n][l]; n>=DI: out2=resT
// MEPI 2: out_proj-> out[m*DM+n] += acc (t fp32) and outb = bf16(new t)
template <int BM, int BN, int MEPI, int NCAP, bool AT>
__global__ __launch_bounds__(256) void k_mgemm(
    const unsigned short* __restrict__ A, const unsigned short* __restrict__ Abf,
    const float* __restrict__ W, float* __restrict__ out,
    float* __restrict__ out2, unsigned short* __restrict__ outb, const int K) {
  constexpr int WM = BM / 2, WN = BN / 2, FM = WM / 16, FN = WN / 16;
  constexpr bool NMASK = (NCAP % BN) != 0;
  __shared__ unsigned short As[BM * 40];
  __shared__ unsigned short Bs[BN * 40];
  const int tid = threadIdx.x;
  const int lane = tid & 63, wave = tid >> 6;
  const int wm = wave >> 1, wn = wave & 1;
  const int m0 = blockIdx.x * BM, n0 = blockIdx.y * BN;
  const int r16 = lane & 15, kg = (lane >> 4) * 8;
  f32x4 acc[FM][FN] = {};
  const int nk = K >> 5;
  for (int kt = 0; kt < nk; ++kt) {
    const int k0 = kt << 5;
    if constexpr (AT) {
      // bf16 [B][K][SL] -> bf16 LDS [m][k], fused transpose (8B loads)
#pragma unroll
      for (int it = 0; it < BM / 64; ++it) {
        const int c = tid + 256 * it;
        const int kp = c & 15;
        const int lq = (c >> 4) * 4;
        const int mrow = m0 + lq;
        const int bb = mrow / SL;
        const size_t rowo = (size_t)(bb * K + k0 + 2 * kp) * SL + (mrow - bb * SL);
        const us4 v0 = *(const us4*)&Abf[rowo];
        const us4 v1 = *(const us4*)&Abf[rowo + SL];
#pragma unroll
        for (int e = 0; e < 4; ++e) {
          const unsigned int pk =
              (unsigned int)v0[e] | ((unsigned int)v1[e] << 16);
          *(unsigned int*)&As[(lq + e) * 40 + 2 * kp] = pk;
        }
      }
    } else {
#pragma unroll
      for (int it = 0; it < (BM * 4) / 256; ++it) {
        const int c = tid + 256 * it;
        const int row = c >> 2, ks = (c & 3) * 8;
        *(short8*)&As[row * 40 + ks] =
            *(const short8*)&A[(size_t)(m0 + row) * K + k0 + ks];
      }
    }
#pragma unroll
    for (int it = 0; it < (BN * 8) / 256; ++it) {
      const int c = tid + 256 * it;
      const int row = c >> 3, ks = (c & 7) * 4;
      float4 v = make_float4(0.f, 0.f, 0.f, 0.f);
      if (!NMASK || (n0 + row) < NCAP)
        v = *(const float4*)&W[(size_t)(n0 + row) * K + k0 + ks];
      short4v o4;
      o4[0] = (short)cvt_bf(v.x);
      o4[1] = (short)cvt_bf(v.y);
      o4[2] = (short)cvt_bf(v.z);
      o4[3] = (short)cvt_bf(v.w);
      *(short4v*)&Bs[row * 40 + ks] = o4;
    }
    __syncthreads();
    short8 af[FM], bfv[FN];
#pragma unroll
    for (int i = 0; i < FM; ++i)
      af[i] = *(const short8*)&As[(wm * WM + i * 16 + r16) * 40 + kg];
#pragma unroll
    for (int j = 0; j < FN; ++j)
      bfv[j] = *(const short8*)&Bs[(wn * WN + j * 16 + r16) * 40 + kg];
#pragma unroll
    for (int i = 0; i < FM; ++i)
#pragma unroll
      for (int j = 0; j < FN; ++j)
        acc[i][j] = __builtin_amdgcn_mfma_f32_16x16x32_bf16(af[i], bfv[j],
                                                            acc[i][j], 0, 0, 0);
    __syncthreads();
  }

#pragma unroll
  for (int i = 0; i < FM; ++i) {
#pragma unroll
    for (int j = 0; j < FN; ++j) {
      const int n = n0 + wn * WN + j * 16 + r16;
      const int mb = m0 + wm * WM + i * 16 + ((lane >> 4) << 2);
      f32x4 a = acc[i][j];
      if (MEPI == 0) {
        if (n < DR) {
#pragma unroll
          for (int r = 0; r < 4; ++r) out[(size_t)(mb + r) * DR + n] = a[r];
        } else if (n < NCAP) {
#pragma unroll
          for (int r = 0; r < 4; ++r) out2[(size_t)(mb + r) * 32 + (n - DR)] = a[r];
        }
      } else if (MEPI == 1) {
        unsigned short* base = (unsigned short*)out;
        int nn = n;
        if (n >= DI) { base = (unsigned short*)out2; nn = n - DI; }
        const int bb = mb / SL;
        const int ll = mb - bb * SL;
        us4 o4;
#pragma unroll
        for (int r = 0; r < 4; ++r) o4[r] = cvt_bf(a[r]);
        *(us4*)&base[((size_t)(bb * DI + nn)) * SL + ll] = o4;
      } else {  // MEPI 2
#pragma unroll
        for (int r = 0; r < 4; ++r) {
          const size_t off = (size_t)(mb + r) * DM + n;
          const float nv = out[off] + a[r];
          out[off] = nv;
          outb[off] = cvt_bf(nv);
        }
      }
    }
  }
}

// ---------------- fp32 SIMT GEMM (dt_proj, K=24) ----------------
template <int EPI, bool KTAIL, int NCAP>
__global__ __launch_bounds__(256) void k_gemm(
    const float* __restrict__ A, const float* __restrict__ W,
    const float* __restrict__ bias, float* __restrict__ out, int K, int lda) {
  __shared__ float sm[4352];
  const int tid = threadIdx.x;
  const int m0 = blockIdx.x * 64;
  const int n0 = blockIdx.y * 64;
  const int b = m0 / SL, l0 = m0 % SL;
  const int tm = tid >> 4, tn = tid & 15;
  float acc[4][4] = {};
  float* As = sm;
  float* Ws = sm + 16 * 68;

  const int nk = (K + 15) / 16;
  for (int kt = 0; kt < nk; ++kt) {
    const int k0 = kt * 16;
    {
      const int row = tid >> 2;
      const int kq = (tid & 3) * 4;
      const int kb = k0 + kq;
      float4 v = make_float4(0.f, 0.f, 0.f, 0.f);
      if (!KTAIL || kb < K) v = *(const float4*)&A[(size_t)(m0 + row) * lda + kb];
      As[(kq + 0) * 68 + row] = v.x;
      As[(kq + 1) * 68 + row] = v.y;
      As[(kq + 2) * 68 + row] = v.z;
      As[(kq + 3) * 68 + row] = v.w;
    }
    {
      const int row = tid >> 2;
      const int kq = (tid & 3) * 4;
      const int kb = k0 + kq;
      float4 v = make_float4(0.f, 0.f, 0.f, 0.f);
      const bool nok = (NCAP % 64 == 0) || (n0 + row < NCAP);
      if (nok && (!KTAIL || kb < K)) v = *(const float4*)&W[(size_t)(n0 + row) * K + kb];
      Ws[(kq + 0) * 68 + row] = v.x;
      Ws[(kq + 1) * 68 + row] = v.y;
      Ws[(kq + 2) * 68 + row] = v.z;
      Ws[(kq + 3) * 68 + row] = v.w;
    }
    __syncthreads();
#pragma unroll
    for (int kk = 0; kk < 16; ++kk) {
      const float4 av = *(const float4*)&As[kk * 68 + 4 * tm];
      const float4 wv = *(const float4*)&Ws[kk * 68 + 4 * tn];
      const float ax[4] = {av.x, av.y, av.z, av.w};
      const float wx[4] = {wv.x, wv.y, wv.z, wv.w};
#pragma unroll
      for (int i = 0; i < 4; ++i)
#pragma unroll
        for (int j = 0; j < 4; ++j) acc[i][j] = fmaf(ax[i], wx[j], acc[i][j]);
    }
    __syncthreads();
  }

#pragma unroll
  for (int j = 0; j < 4; ++j) {
    const int nn = 4 * tn + j;
#pragma unroll
    for (int i = 0; i < 4; ++i) {
      float v = acc[i][j];
      if (EPI == 2) v = softplusf(v + bias[n0 + nn]);
      sm[nn * 68 + 4 * tm + i] = v;
    }
  }
  __syncthreads();
  const int row = tid >> 2;
  const int seg = (tid & 3) * 16;
  const float* src = &sm[row * 68 + seg];
  float* dst = out + ((size_t)(b * DI + n0 + row)) * SL + l0 + seg;
#pragma unroll
  for (int q = 0; q < 4; ++q) {
    *(float4*)&dst[q * 4] = *(const float4*)&src[q * 4];
  }
}

// ------------- depthwise causal conv1d + bias + silu (bf16 in/out) -------------
__global__ void k_conv(const unsigned short* __restrict__ xcT,
                       const float* __restrict__ cw, const float* __restrict__ cb,
                       unsigned short* __restrict__ uT) {
  const size_t idx = (size_t)blockIdx.x * 256 + threadIdx.x;
  const int l4 = (int)(idx % (SL / 4)) * 4;
  const int bd = (int)(idx / (SL / 4));
  const int d = bd % DI;
  const unsigned short* row = xcT + (size_t)bd * SL;
  const float4 w = *(const float4*)&cw[d * 4];
  const us4 cu = *(const us4*)&row[l4];
  const float c0 = bf2f(cu[0]), c1 = bf2f(cu[1]), c2 = bf2f(cu[2]), c3 = bf2f(cu[3]);
  float p1 = 0.f, p2 = 0.f, p3 = 0.f;
  if (l4 > 0) {
    const us4 pv = *(const us4*)&row[l4 - 4];
    p1 = bf2f(pv[1]); p2 = bf2f(pv[2]); p3 = bf2f(pv[3]);
  }
  const float cbd = cb[d];
  float o0 = cbd + w.w * c0 + w.z * p3 + w.y * p2 + w.x * p1;
  float o1 = cbd + w.w * c1 + w.z * c0 + w.y * p3 + w.x * p2;
  float o2 = cbd + w.w * c2 + w.z * c1 + w.y * c0 + w.x * p3;
  float o3 = cbd + w.w * c3 + w.z * c2 + w.y * c1 + w.x * c0;
  us4 o4;
  o4[0] = cvt_bf(siluf(o0));
  o4[1] = cvt_bf(siluf(o1));
  o4[2] = cvt_bf(siluf(o2));
  o4[3] = cvt_bf(siluf(o3));
  *(us4*)&uT[(size_t)bd * SL + l4] = o4;
}

// ---------------- wave-synchronous fused selective scan -----------------------
__global__ __launch_bounds__(256) void k_scanw(
    const float* __restrict__ deltaT, const unsigned short* __restrict__ uT,
    const float* __restrict__ BC, const unsigned short* __restrict__ resT,
    const float* __restrict__ A_log, const float* __restrict__ Dp,
    unsigned short* __restrict__ yT) {
  const int tid = threadIdx.x;
  const int lane = tid & 63, wv = tid >> 6;
  const int n = lane & 15, g = lane >> 4;
  const int chain = blockIdx.x * 4 + wv;
  const int b = chain / DI, d = chain % DI;
  const float a2 = -expf(A_log[d * DSN + n]) * 1.44269504088896341f;
  const float dp = Dp[d];
  const float* drow = deltaT + (size_t)chain * SL;
  const unsigned short* urow = uT + (size_t)chain * SL;
  const unsigned short* resr = resT + (size_t)chain * SL;
  const float* bcb = BC + (size_t)b * SL * 32;
  unsigned short* yr = yT + (size_t)chain * SL;
  float carry = 0.f;
  const bool b0 = n & 1, b1 = (n >> 1) & 1, b2 = (n >> 2) & 1, b3 = (n >> 3) & 1;

  for (int tb = 0; tb < SL; tb += 64) {
    const int l0 = tb + g * 16;
    float da[16], dbu[16];
    float h = 0.f, dsum = 0.f;
#pragma unroll
    for (int k = 0; k < 16; ++k) {
      const float dl = drow[l0 + k];
      const float ul = bf2f(urow[l0 + k]);
      const float Bv = bcb[(size_t)(l0 + k) * 32 + n];
      const float e = exp2f(dl * a2);
      da[k] = e;
      dbu[k] = dl * ul * Bv;
      h = fmaf(e, h, dbu[k]);
      dsum += dl;
    }
    float Aagg = exp2f(a2 * dsum);
    float Bagg = h;
#pragma unroll
    for (int off = 16; off <= 32; off <<= 1) {
      const float Ae = __shfl(Aagg, (lane - off) & 63);
      const float Be = __shfl(Bagg, (lane - off) & 63);
      if (lane >= off) {
        Bagg = fmaf(Aagg, Be, Bagg);
        Aagg *= Ae;
      }
    }
    const float Pa = __shfl(Aagg, (lane - 16) & 63);
    const float Pb = __shfl(Bagg, (lane - 16) & 63);
    const float hstart = (g == 0) ? carry : fmaf(Pa, carry, Pb);
    const float cA = __shfl(Aagg, 48 | n);
    const float cB = __shfl(Bagg, 48 | n);
    float p[16];
    h = hstart;
#pragma unroll
    for (int k = 0; k < 16; ++k) {
      h = fmaf(da[k], h, dbu[k]);
      p[k] = h * bcb[(size_t)(l0 + k) * 32 + 16 + n];
    }
    carry = fmaf(cA, carry, cB);
    // stream-merging reduction over the 16 state lanes
    float q8[8];
#pragma unroll
    for (int i = 0; i < 8; ++i) {
      const float mine = b0 ? p[2 * i + 1] : p[2 * i];
      const float oth = b0 ? p[2 * i] : p[2 * i + 1];
      q8[i] = mine + __shfl_xor(oth, 1);
    }
    float q4[4];
#pragma unroll
    for (int i = 0; i < 4; ++i) {
      const float mine = b1 ? q8[2 * i + 1] : q8[2 * i];
      const float oth = b1 ? q8[2 * i] : q8[2 * i + 1];
      q4[i] = mine + __shfl_xor(oth, 2);
    }
    float q2[2];
#pragma unroll
    for (int i = 0; i < 2; ++i) {
      const float mine = b2 ? q4[2 * i + 1] : q4[2 * i];
      const float oth = b2 ? q4[2 * i] : q4[2 * i + 1];
      q2[i] = mine + __shfl_xor(oth, 4);
    }
    const float mine = b3 ? q2[1] : q2[0];
    const float oth = b3 ? q2[0] : q2[1];
    const float ysum = mine + __shfl_xor(oth, 8);
    const float uln = bf2f(urow[l0 + n]);
    const float r = bf2f(resr[l0 + n]);
    yr[l0 + n] = cvt_bf((ysum + uln * dp) * siluf(r));
  }
}

// ---------------- RMS denom ----------------
__global__ void k_rinv(const float* __restrict__ t, float* __restrict__ rinv) {
  const int row = blockIdx.x;
  const float* tr = t + (size_t)row * DM;
  const int tid = threadIdx.x;
  float ss = 0.f;
#pragma unroll
  for (int k = 0; k < DM / 64; ++k) {
    const float v = tr[tid + k * 64];
    ss = fmaf(v, v, ss);
  }
  ss += __shfl_xor(ss, 1);
  ss += __shfl_xor(ss, 2);
  ss += __shfl_xor(ss, 4);
  ss += __shfl_xor(ss, 8);
  ss += __shfl_xor(ss, 16);
  ss += __shfl_xor(ss, 32);
  if (tid == 0) rinv[row] = 1.f / sqrtf(ss / DM + 1e-5f);
}

// ---------------- pooled partial sums ----------------
__global__ void k_pool(const float* __restrict__ t, const float* __restrict__ rinv,
                       float* __restrict__ part) {
  const int b = blockIdx.x, dmb = blockIdx.y, ch = blockIdx.z;
  const int dm = dmb * 64 + threadIdx.x;
  const int lbeg = ch * (SL / 32);
  float s = 0.f;
  for (int l = lbeg; l < lbeg + SL / 32; ++l)
    s = fmaf(t[((size_t)b * SL + l) * DM + dm], rinv[b * SL + l], s);
  part[((size_t)ch * NB + b) * DM + dm] = s;
}

// ---------------- head ----------------
__global__ void k_head(const float* __restrict__ part, const float* __restrict__ norm_w,
                       const float* __restrict__ hw, const float* __restrict__ hb,
                       float* __restrict__ out) {
  const int b = blockIdx.x;
  const int tid = threadIdx.x;
  __shared__ float pv[DM];
  for (int k = tid; k < DM; k += 64) {
    float s = 0.f;
#pragma unroll
    for (int c = 0; c < 32; ++c) s += part[((size_t)c * NB + b) * DM + k];
    pv[k] = s * norm_w[k] * (1.f / SL);
  }
  __syncthreads();
  const int cls = blockIdx.y * 64 + tid;
  if (cls < NCLS) {
    const float* wr = hw + (size_t)cls * DM;
    float acc = hb[cls];
#pragma unroll 4
    for (int k = 0; k < DM; k += 4) {
      const float4 w4 = *(const float4*)&wr[k];
      acc = fmaf(pv[k], w4.x, acc);
      acc = fmaf(pv[k + 1], w4.y, acc);
      acc = fmaf(pv[k + 2], w4.z, acc);
      acc = fmaf(pv[k + 3], w4.w, acc);
    }
    out[(size_t)b * NCLS + cls] = acc;
  }
}

extern "C" void kernel_launch(void* const* d_in, const int* in_sizes, int n_in,
                              void* d_out, int out_size, void* d_ws, size_t ws_size,
                              hipStream_t stream) {
  (void)in_sizes; (void)n_in; (void)out_size; (void)ws_size;
  const float* x = (const float*)d_in[0];
  const float* patch_w = (const float*)d_in[1];
  const float* patch_b = (const float*)d_in[2];
  const float* in_proj_w = (const float*)d_in[3];
  const float* conv_w = (const float*)d_in[4];
  const float* conv_b = (const float*)d_in[5];
  const float* x_proj_w = (const float*)d_in[6];
  const float* dt_proj_w = (const float*)d_in[7];
  const float* dt_proj_b = (const float*)d_in[8];
  const float* A_log = (const float*)d_in[9];
  const float* Dp = (const float*)d_in[10];
  const float* out_proj_w = (const float*)d_in[11];
  const float* norm_w = (const float*)d_in[12];
  const float* head_w = (const float*)d_in[13];
  const float* head_b = (const float*)d_in[14];

  float* ws = (float*)d_ws;
  size_t o = 0;
  float* t = ws + o;     o += (size_t)NB * SL * DM;
  // bf16 buffers (each NB*DI*SL ushort = NB*DI*SL/2 floats)
  unsigned short* xcT = (unsigned short*)(ws + o);  o += (size_t)NB * DI * SL / 2;
  unsigned short* resT = (unsigned short*)(ws + o); o += (size_t)NB * DI * SL / 2;
  unsigned short* uT = (unsigned short*)(ws + o);   o += (size_t)NB * DI * SL / 2;
  unsigned short* yT = (unsigned short*)(ws + o);   o += (size_t)NB * DI * SL / 2;
  float* dltT = ws + o;  o += (size_t)NB * DI * SL;
  float* dbl24 = ws + o; o += (size_t)NB * SL * DR;
  float* BC = ws + o;    o += (size_t)NB * SL * 32;
  float* rinv = ws + o;  o += (size_t)NB * SL;
  float* part = ws + o;  o += (size_t)32 * NB * DM;
  unsigned short* tb = (unsigned short*)(ws + o); o += (size_t)NB * SL * DM / 2;

  k_patch<<<(NB * SL) / PTOK, 128, 0, stream>>>(x, patch_w, patch_b, t, tb);

  for (int i = 0; i < NLAYER; ++i) {
    // in_proj: tb[M,384](bf16) x W[1536,384]^T -> xcT / resT (bf16, [b][n][l])
    k_mgemm<128, 128, 1, 1536, false><<<dim3(98, 12), 256, 0, stream>>>(
        tb, nullptr, in_proj_w + (size_t)i * 2 * DI * DM, (float*)xcT, (float*)resT,
        nullptr, DM);
    // depthwise causal conv + silu -> uT (bf16)
    k_conv<<<(NB * DI * SL / 4) / 256, 256, 0, stream>>>(
        xcT, conv_w + (size_t)i * DI * 4, conv_b + (size_t)i * DI, uT);
    // x_proj: uT (bf16 AT-staged) x W[56,768]^T -> dbl24 + BC[b][l][32]
    k_mgemm<64, 64, 0, XPN, true><<<dim3(196, 1), 256, 0, stream>>>(
        nullptr, uT, x_proj_w + (size_t)i * XPN * DI, dbl24, BC, nullptr, DI);
    // dt_proj (fp32 SIMT): softplus(dbl24 @ dt_w^T + b) -> dltT [b][d][l] fp32
    k_gemm<2, true, 64><<<dim3(196, 12), 256, 0, stream>>>(
        dbl24, dt_proj_w + (size_t)i * DI * DR, dt_proj_b + (size_t)i * DI, dltT,
        DR, DR);
    // wave-synchronous fused selective scan + gate -> yT (bf16)
    k_scanw<<<NCHAIN / 4, 256, 0, stream>>>(
        dltT, uT, BC, resT, A_log + (size_t)i * DI * DSN, Dp + (size_t)i * DI, yT);
    // out_proj: yT (bf16 AT-staged) x W[384,768]^T -> t += ; tb = bf16(t)
    k_mgemm<128, 128, 2, 384, true><<<dim3(98, 3), 256, 0, stream>>>(
        nullptr, yT, out_proj_w + (size_t)i * DM * DI, t, nullptr, tb, DI);
  }

  k_rinv<<<NB * SL, 64, 0, stream>>>(t, rinv);
  k_pool<<<dim3(NB, DM / 64, 32), 64, 0, stream>>>(t, rinv, part);
  k_head<<<dim3(NB, 16), 64, 0, stream>>>(part, norm_w, head_w, head_b, (float*)d_out);
}